// Round 7
// baseline (2160.058 us; speedup 1.0000x reference)
//
#include <hip/hip_runtime.h>
#include <cstdint>
#include <cstddef>

#define TT 4
#define BB 8
#define CC 256
#define NN 1024
#define HEADS 8
#define DD 32

typedef __attribute__((ext_vector_type(4))) double f64x4;
typedef __attribute__((ext_vector_type(8))) float  f32x8;

// Fused conv1x1 (GEMM) + BatchNorm + LIF-over-time using fp64 MFMA.
// Block: 32(o) x 32(n) tile, 4 waves; wave w computes timestep t=w.
// W is NOT staged in LDS: each lane register-double-buffers its 16 A-operand
// floats straight from global (L1-hot, shared across n-blocks).
// LDS = X double-buffer only, 32768 B exactly -> 5 blocks/CU. X tiles use
// additive column-rotate swizzle col' = (n + 8*(k&3)) & 31 (reads 2-way=free).
// Reg-staged issue-early/write-late X pipeline, 1 barrier/K-step.
// C/D mapping of v_mfma_f64_16x16x4f64 recovered at runtime via probes.
template<typename InT, typename OutT, bool HAS_BIAS, bool ADD_BASE, bool TRIPLE>
__global__ __launch_bounds__(256, 5) void conv_bn_lif_mfma(
    const float* __restrict__ W0, const float* __restrict__ W1,
    const float* __restrict__ W2, const float* __restrict__ bias,
    const float* __restrict__ bn0, const float* __restrict__ bn1,
    const float* __restrict__ bn2,
    const InT* __restrict__ X,
    OutT* __restrict__ Out0, OutT* __restrict__ Out1, OutT* __restrict__ Out2,
    const float* __restrict__ base,   // [T, B, O, N] (ADD_BASE) or null
    int O, int CIN)
{
    __shared__ __align__(16) float Xs[2][TT][32][32];  // [buf][t][k][c'] swizzled, 32768 B
    double* pre = (double*)&Xs[0][0][0][0];            // [4][32][32] f64 overlay (32 KB)

    const int tid  = threadIdx.x;
    const int lane = tid & 63;
    const int wave = tid >> 6;          // == timestep t for the GEMM phase
    const int col  = lane & 15;
    const int rowg = lane >> 4;         // 0..3  (k-group)
    const int n0 = blockIdx.x * 32;
    const int b  = blockIdx.z;

    int o0;
    const float *W, *bn;
    OutT* Out;
    if constexpr (TRIPLE) {
        const int sel = blockIdx.y >> 3;
        o0 = (blockIdx.y & 7) * 32;
        W   = sel == 0 ? W0  : (sel == 1 ? W1  : W2);
        bn  = sel == 0 ? bn0 : (sel == 1 ? bn1 : bn2);
        Out = sel == 0 ? Out0 : (sel == 1 ? Out1 : Out2);
    } else {
        o0 = blockIdx.y * 32;
        W = W0; bn = bn0; Out = Out0;
    }

    // X staging thread mapping (fixed across iterations)
    const int x_kk = tid >> 3, x_n4 = tid & 7;           // X: [32 k][8 n-quads] per t
    const int xsw  = (x_n4 * 4 + 8 * (x_kk & 3)) & 31;   // swizzled col for X write

    // per-thread swizzled read columns for X (B-operand)
    const int cb0 = (col + 8 * rowg) & 31;
    const int cb1 = (col + 16 + 8 * rowg) & 31;

    // W A-operand row bases for this lane (o = o0+col and o0+col+16)
    const float* Wrow0 = &W[(size_t)(o0 + col) * CIN + rowg];
    const float* Wrow1 = &W[(size_t)(o0 + col + 16) * CIN + rowg];

    // ---- runtime layout probes (exact integer arithmetic in f64) ----
    f64x4 p1 = {0.0, 0.0, 0.0, 0.0};
    f64x4 p2 = {0.0, 0.0, 0.0, 0.0};
    const double lanev = (double)col;
    p1 = __builtin_amdgcn_mfma_f64_16x16x4f64(lanev, 1.0, p1, 0, 0, 0);
    p2 = __builtin_amdgcn_mfma_f64_16x16x4f64(1.0, lanev, p2, 0, 0, 0);
    int o_idx[4], n_idx[4];
#pragma unroll
    for (int r = 0; r < 4; ++r) {
        o_idx[r] = (int)(p1[r] * 0.25);   // which A-row (o within 16) reg r holds
        n_idx[r] = (int)(p2[r] * 0.25);   // which B-col (n within 16) reg r holds
    }

    f64x4 acc[2][2];                      // [mf][nf] for t = wave
#pragma unroll
    for (int mf = 0; mf < 2; ++mf)
#pragma unroll
        for (int nf = 0; nf < 2; ++nf)
            acc[mf][nf] = (f64x4){0.0, 0.0, 0.0, 0.0};

    // in-flight staging registers
    float4 rX[TT];
    uchar4 rXu[TT];
    f32x8 waC0, waC1, waN0, waN1;         // W operands: current / next K-step

    auto issue_x = [&](int c0) {
#pragma unroll
        for (int j = 0; j < TT; ++j) {
            const size_t goff =
                (((size_t)j * BB + b) * CIN + c0 + x_kk) * NN + n0 + x_n4 * 4;
            if constexpr (__is_same(InT, uint8_t)) {
                rXu[j] = *reinterpret_cast<const uchar4*>(&X[goff]);
            } else {
                rX[j] = *reinterpret_cast<const float4*>(&X[goff]);
            }
        }
    };
    auto write_x = [&](int buf) {
#pragma unroll
        for (int j = 0; j < TT; ++j) {
            float4 xv;
            if constexpr (__is_same(InT, uint8_t)) {
                xv = make_float4((float)rXu[j].x, (float)rXu[j].y,
                                 (float)rXu[j].z, (float)rXu[j].w);
            } else {
                xv = rX[j];
            }
            *reinterpret_cast<float4*>(&Xs[buf][j][x_kk][xsw]) = xv;
        }
    };
    auto load_w = [&](int c0, f32x8& a0, f32x8& a1) {
#pragma unroll
        for (int kq = 0; kq < 8; ++kq) {
            a0[kq] = Wrow0[c0 + kq * 4];
            a1[kq] = Wrow1[c0 + kq * 4];
        }
    };

    // prologue: stage X tile 0, load W operands for tile 0
    issue_x(0);
    load_w(0, waC0, waC1);
    write_x(0);
    __syncthreads();

    int cur = 0;
    for (int c0 = 32; c0 <= CIN; c0 += 32) {
        const bool has_next = (c0 < CIN);
        if (has_next) {
            issue_x(c0);                    // issue-early (hidden under MFMA)
            load_w(c0, waN0, waN1);         // next K-step's A operands (L1-hot)
        }
        __builtin_amdgcn_s_setprio(1);
#pragma unroll
        for (int kq = 0; kq < 8; ++kq) {
            const int kr = kq * 4 + rowg;
            double av0 = (double)waC0[kq];
            double av1 = (double)waC1[kq];
            double bv0 = (double)Xs[cur][wave][kr][cb0];
            double bv1 = (double)Xs[cur][wave][kr][cb1];
            acc[0][0] = __builtin_amdgcn_mfma_f64_16x16x4f64(av0, bv0, acc[0][0], 0, 0, 0);
            acc[1][0] = __builtin_amdgcn_mfma_f64_16x16x4f64(av1, bv0, acc[1][0], 0, 0, 0);
            acc[0][1] = __builtin_amdgcn_mfma_f64_16x16x4f64(av0, bv1, acc[0][1], 0, 0, 0);
            acc[1][1] = __builtin_amdgcn_mfma_f64_16x16x4f64(av1, bv1, acc[1][1], 0, 0, 0);
        }
        __builtin_amdgcn_s_setprio(0);
        if (has_next) write_x(cur ^ 1);     // write-late
        __syncthreads();                    // single barrier per K-step
        cur ^= 1;
        waC0 = waN0; waC1 = waN1;
    }

    // ---- epilogue: dump pre-activations to LDS (probe-indexed) ----
#pragma unroll
    for (int mf = 0; mf < 2; ++mf)
#pragma unroll
        for (int r = 0; r < 4; ++r)
#pragma unroll
            for (int nf = 0; nf < 2; ++nf)
                pre[((size_t)wave * 32 + mf * 16 + o_idx[r]) * 32
                    + nf * 16 + n_idx[r]] = acc[mf][nf][r];
    __syncthreads();

    // ---- BN + LIF (tau=2, hard reset, v_th=1): 4 outputs x 4 t per thread ----
    const int nl = tid & 31;
    const int obase = (tid >> 5) * 4;
#pragma unroll
    for (int i = 0; i < 4; ++i) {
        const int ol = obase + i;
        const int o  = o0 + ol;
        const double g   = (double)bn[0 * O + o];
        const double be  = (double)bn[1 * O + o];
        const double mu  = (double)bn[2 * O + o];
        const double var = (double)bn[3 * O + o];
        const double scale = g / sqrt(var + 1e-5);
        double bi = 0.0;
        if constexpr (HAS_BIAS) bi = (double)bias[o];
        double v = 0.0;
#pragma unroll
        for (int t = 0; t < TT; ++t) {
            double val = (pre[((size_t)t * 32 + ol) * 32 + nl] + bi - mu) * scale + be;
            v = v + (val - v) * 0.5;
            double s = (v >= 1.0) ? 1.0 : 0.0;
            size_t idx = (((size_t)t * BB + b) * O + o) * NN + n0 + nl;
            if constexpr (ADD_BASE) {
                Out[idx] = (OutT)((double)base[idx] + s);
            } else {
                Out[idx] = (OutT)s;
            }
            v = v * (1.0 - s);
        }
    }
}

// kv[t,b,h,d,e] = sum_n k[t,b,h*32+d,n] * v[t,b,h*32+e,n]  (exact int in fp32)
__global__ __launch_bounds__(256) void kv_kernel(
    const float* __restrict__ k_s, const float* __restrict__ v_s,
    float* __restrict__ kv)
{
    const int blk = blockIdx.x;          // (t*BB+b)*HEADS + h
    const int h = blk & 7;
    const int m = blk >> 3;              // t*BB + b
    __shared__ float ks[32][65];
    __shared__ float vs[32][65];
    const int tid = threadIdx.x;
    const int d = tid >> 3;
    const int e0 = (tid & 7) * 4;
    float acc[4] = {0.f, 0.f, 0.f, 0.f};
    const size_t basek = ((size_t)m * CC + h * DD) * NN;
    for (int nc = 0; nc < NN; nc += 64) {
        for (int i = tid; i < 2048; i += 256) {
            int r = i >> 6, nl = i & 63;
            ks[r][nl] = k_s[basek + (size_t)r * NN + nc + nl];
            vs[r][nl] = v_s[basek + (size_t)r * NN + nc + nl];
        }
        __syncthreads();
        for (int nl = 0; nl < 64; ++nl) {
            float kd = ks[d][nl];
#pragma unroll
            for (int j = 0; j < 4; ++j) acc[j] += kd * vs[e0 + j][nl];
        }
        __syncthreads();
    }
#pragma unroll
    for (int j = 0; j < 4; ++j)
        kv[(size_t)blk * 1024 + d * 32 + e0 + j] = acc[j];
}

// a = 0.125 * q @ kv -> LIF(v_th=0.5); exact dyadic arithmetic in fp32.
__global__ __launch_bounds__(256) void attn_a_lif(
    const float* __restrict__ q_s, const float* __restrict__ kv,
    float* __restrict__ a_s)
{
    const int tid = threadIdx.x;
    const int n = blockIdx.x * 256 + tid;
    const int c = blockIdx.y;
    const int b = blockIdx.z;
    const int h = c >> 5;
    const int e = c & 31;
    __shared__ float kvs[TT][32];
    if (tid < 128) {
        int t = tid >> 5, d2 = tid & 31;
        kvs[t][d2] = kv[(((size_t)t * BB + b) * HEADS + h) * 1024 + d2 * 32 + e];
    }
    __syncthreads();
    float val[TT];
#pragma unroll
    for (int t = 0; t < TT; ++t) {
        float s = 0.f;
        const size_t qb = (((size_t)t * BB + b) * CC + h * DD) * NN + n;
#pragma unroll 8
        for (int d2 = 0; d2 < 32; ++d2)
            s += q_s[qb + (size_t)d2 * NN] * kvs[t][d2];
        val[t] = s * 0.125f;
    }
    float v = 0.f;
#pragma unroll
    for (int t = 0; t < TT; ++t) {
        v = v + (val[t] - v) * 0.5f;
        float s = (v >= 0.5f) ? 1.f : 0.f;
        a_s[(((size_t)t * BB + b) * CC + c) * NN + n] = s;
        v = v * (1.f - s);
    }
}

extern "C" void kernel_launch(void* const* d_in, const int* in_sizes, int n_in,
                              void* d_out, int out_size, void* d_ws, size_t ws_size,
                              hipStream_t stream)
{
    const float* x       = (const float*)d_in[0];
    const float* q_w     = (const float*)d_in[1];
    const float* q_bn    = (const float*)d_in[2];
    const float* k_w     = (const float*)d_in[3];
    const float* k_bn    = (const float*)d_in[4];
    const float* v_w     = (const float*)d_in[5];
    const float* v_bn    = (const float*)d_in[6];
    const float* proj_w  = (const float*)d_in[7];
    const float* proj_b  = (const float*)d_in[8];
    const float* proj_bn = (const float*)d_in[9];
    const float* mlp1_w  = (const float*)d_in[10];
    const float* mlp1_b  = (const float*)d_in[11];
    const float* mlp1_bn = (const float*)d_in[12];
    const float* mlp2_w  = (const float*)d_in[13];
    const float* mlp2_b  = (const float*)d_in[14];
    const float* mlp2_bn = (const float*)d_in[15];

    const size_t SZ = (size_t)TT * BB * CC * NN;   // 8388608 elements
    char* ws = (char*)d_ws;
    float*   q_s   = (float*)(ws);
    float*   k_s   = (float*)(ws + SZ * 4);
    float*   v_s   = (float*)(ws + 2 * SZ * 4);
    float*   a_s   = (float*)(ws + 3 * SZ * 4);
    float*   kvb   = (float*)(ws + 4 * SZ * 4);    // 1 MB
    float*   x_new = (float*)(ws);                 // reuses q_s region
    uint8_t* h1    = (uint8_t*)(ws + SZ * 4);      // reuses k_s region (33.5 MB)

    dim3 blk(256);
    dim3 gqkv(NN / 32, 3 * 256 / 32, BB);  // (32, 24, 8) fused q/k/v
    dim3 g256(NN / 32, 256 / 32, BB);      // (32, 8, 8)
    dim3 g1024(NN / 32, 1024 / 32, BB);    // (32, 32, 8)

    // Q/K/V conv + BN + LIF -> spike trains (f32 0/1), one fused dispatch
    conv_bn_lif_mfma<float, float, false, false, true><<<gqkv, blk, 0, stream>>>(
        q_w, k_w, v_w, nullptr, q_bn, k_bn, v_bn, x, q_s, k_s, v_s,
        nullptr, 256, 256);

    // attention: kv = k^T v, then a = 0.125 * q kv -> LIF(0.5)
    kv_kernel<<<dim3(TT * BB * HEADS), blk, 0, stream>>>(k_s, v_s, kvb);
    attn_a_lif<<<dim3(4, 256, 8), blk, 0, stream>>>(q_s, kvb, a_s);

    // proj conv + bias + BN + LIF, fused residual: x_new = x + ssa
    conv_bn_lif_mfma<float, float, true, true, false><<<g256, blk, 0, stream>>>(
        proj_w, nullptr, nullptr, proj_b, proj_bn, nullptr, nullptr, a_s,
        x_new, nullptr, nullptr, x, 256, 256);

    // MLP: 256 -> 1024 (spikes as uint8) -> 256, fused residual to d_out
    conv_bn_lif_mfma<float, uint8_t, true, false, false><<<g1024, blk, 0, stream>>>(
        mlp1_w, nullptr, nullptr, mlp1_b, mlp1_bn, nullptr, nullptr, x_new,
        h1, nullptr, nullptr, nullptr, 1024, 256);
    conv_bn_lif_mfma<uint8_t, float, true, true, false><<<g256, blk, 0, stream>>>(
        mlp2_w, nullptr, nullptr, mlp2_b, mlp2_bn, nullptr, nullptr, h1,
        (float*)d_out, nullptr, nullptr, x_new, 256, 1024);
}

// Round 8
// 1640.237 us; speedup vs baseline: 1.3169x; 1.3169x over previous
//
#include <hip/hip_runtime.h>
#include <cstdint>
#include <cstddef>

#define TT 4
#define BB 8
#define CC 256
#define NN 1024
#define HEADS 8
#define DD 32

typedef __attribute__((ext_vector_type(4))) double f64x4;
typedef __attribute__((ext_vector_type(8))) float  f32x8;

// Fused conv1x1 (GEMM) + BatchNorm + LIF-over-time using fp64 MFMA.
// Block: 32(o) x 32(n) tile, 4 waves; wave w computes timestep t=w.
// NO LDS for GEMM operands and NO barriers in the K-loop: each lane loads
// its 16 A-floats (W, 2 rows) and 16 B-floats (X, 2 cols) per K-step
// directly from global (L1/L2-hot: W lines shared by all 4 waves, X rows
// are single 128B lines reused across o-blocks) into a register
// double-buffer. Waves run fully decoupled -> MFMA pipe stays fed.
// LDS holds only the f64 pre-activation exchange for the LIF epilogue.
// C/D mapping of v_mfma_f64_16x16x4f64 recovered at runtime via probes.
template<typename InT, typename OutT, bool HAS_BIAS, bool ADD_BASE, bool TRIPLE, int CIN>
__global__ __launch_bounds__(256, 4) void conv_bn_lif_mfma(
    const float* __restrict__ W0, const float* __restrict__ W1,
    const float* __restrict__ W2, const float* __restrict__ bias,
    const float* __restrict__ bn0, const float* __restrict__ bn1,
    const float* __restrict__ bn2,
    const InT* __restrict__ X,
    OutT* __restrict__ Out0, OutT* __restrict__ Out1, OutT* __restrict__ Out2,
    const float* __restrict__ base,   // [T, B, O, N] (ADD_BASE) or null
    int O)
{
    __shared__ double pre[TT][32][32];   // 32768 B: t-plane exchange for LIF

    const int tid  = threadIdx.x;
    const int lane = tid & 63;
    const int wave = tid >> 6;          // == timestep t for the GEMM phase
    const int col  = lane & 15;
    const int rowg = lane >> 4;         // 0..3  (k-group)
    const int n0 = blockIdx.x * 32;
    const int b  = blockIdx.z;

    int o0;
    const float *W, *bn;
    OutT* Out;
    if constexpr (TRIPLE) {
        const int sel = blockIdx.y >> 3;
        o0 = (blockIdx.y & 7) * 32;
        W   = sel == 0 ? W0  : (sel == 1 ? W1  : W2);
        bn  = sel == 0 ? bn0 : (sel == 1 ? bn1 : bn2);
        Out = sel == 0 ? Out0 : (sel == 1 ? Out1 : Out2);
    } else {
        o0 = blockIdx.y * 32;
        W = W0; bn = bn0; Out = Out0;
    }

    // ---- runtime layout probes (exact integer arithmetic in f64) ----
    f64x4 p1 = {0.0, 0.0, 0.0, 0.0};
    f64x4 p2 = {0.0, 0.0, 0.0, 0.0};
    const double lanev = (double)col;
    p1 = __builtin_amdgcn_mfma_f64_16x16x4f64(lanev, 1.0, p1, 0, 0, 0);
    p2 = __builtin_amdgcn_mfma_f64_16x16x4f64(1.0, lanev, p2, 0, 0, 0);
    int o_idx[4], n_idx[4];
#pragma unroll
    for (int r = 0; r < 4; ++r) {
        o_idx[r] = (int)(p1[r] * 0.25);   // which A-row (o within 16) reg r holds
        n_idx[r] = (int)(p2[r] * 0.25);   // which B-col (n within 16) reg r holds
    }

    f64x4 acc[2][2];                      // [mf][nf] for t = wave
#pragma unroll
    for (int mf = 0; mf < 2; ++mf)
#pragma unroll
        for (int nf = 0; nf < 2; ++nf)
            acc[mf][nf] = (f64x4){0.0, 0.0, 0.0, 0.0};

    // per-lane operand base pointers
    const float* Wr0 = W + (size_t)(o0 + col) * CIN + rowg;
    const float* Wr1 = W + (size_t)(o0 + col + 16) * CIN + rowg;
    const InT*   Xr  = X + (((size_t)wave * BB + b) * CIN + rowg) * NN + n0 + col;

    f32x8 wc0, wc1, xc0, xc1;             // current K-step operands
    f32x8 wn0, wn1, xn0, xn1;             // next K-step operands

    auto load_blk = [&](int c0, f32x8& a0, f32x8& a1, f32x8& b0v, f32x8& b1v) {
#pragma unroll
        for (int kq = 0; kq < 8; ++kq) {
            const int kk = c0 + kq * 4;
            a0[kq] = Wr0[kk];
            a1[kq] = Wr1[kk];
            const size_t xo = (size_t)kk * NN;
            if constexpr (__is_same(InT, uint8_t)) {
                b0v[kq] = (float)Xr[xo];
                b1v[kq] = (float)Xr[xo + 16];
            } else {
                b0v[kq] = Xr[xo];
                b1v[kq] = Xr[xo + 16];
            }
        }
    };

    load_blk(0, wc0, wc1, xc0, xc1);
#pragma unroll 2
    for (int c0 = 32; c0 <= CIN; c0 += 32) {
        if (c0 < CIN) load_blk(c0, wn0, wn1, xn0, xn1);   // prefetch next
        __builtin_amdgcn_s_setprio(1);
#pragma unroll
        for (int kq = 0; kq < 8; ++kq) {
            double av0 = (double)wc0[kq];
            double av1 = (double)wc1[kq];
            double bv0 = (double)xc0[kq];
            double bv1 = (double)xc1[kq];
            acc[0][0] = __builtin_amdgcn_mfma_f64_16x16x4f64(av0, bv0, acc[0][0], 0, 0, 0);
            acc[1][0] = __builtin_amdgcn_mfma_f64_16x16x4f64(av1, bv0, acc[1][0], 0, 0, 0);
            acc[0][1] = __builtin_amdgcn_mfma_f64_16x16x4f64(av0, bv1, acc[0][1], 0, 0, 0);
            acc[1][1] = __builtin_amdgcn_mfma_f64_16x16x4f64(av1, bv1, acc[1][1], 0, 0, 0);
        }
        __builtin_amdgcn_s_setprio(0);
        wc0 = wn0; wc1 = wn1; xc0 = xn0; xc1 = xn1;
    }

    // ---- epilogue: each wave dumps its t-plane (probe-indexed) ----
#pragma unroll
    for (int mf = 0; mf < 2; ++mf)
#pragma unroll
        for (int r = 0; r < 4; ++r)
#pragma unroll
            for (int nf = 0; nf < 2; ++nf)
                pre[wave][mf * 16 + o_idx[r]][nf * 16 + n_idx[r]] = acc[mf][nf][r];
    __syncthreads();

    // ---- BN + LIF (tau=2, hard reset, v_th=1): 4 outputs x 4 t per thread ----
    const int nl = tid & 31;
    const int obase = (tid >> 5) * 4;
#pragma unroll
    for (int i = 0; i < 4; ++i) {
        const int ol = obase + i;
        const int o  = o0 + ol;
        const double g   = (double)bn[0 * O + o];
        const double be  = (double)bn[1 * O + o];
        const double mu  = (double)bn[2 * O + o];
        const double var = (double)bn[3 * O + o];
        const double scale = g / sqrt(var + 1e-5);
        double bi = 0.0;
        if constexpr (HAS_BIAS) bi = (double)bias[o];
        double v = 0.0;
#pragma unroll
        for (int t = 0; t < TT; ++t) {
            double val = (pre[t][ol][nl] + bi - mu) * scale + be;
            v = v + (val - v) * 0.5;
            double s = (v >= 1.0) ? 1.0 : 0.0;
            size_t idx = (((size_t)t * BB + b) * O + o) * NN + n0 + nl;
            if constexpr (ADD_BASE) {
                Out[idx] = (OutT)((double)base[idx] + s);
            } else {
                Out[idx] = (OutT)s;
            }
            v = v * (1.0 - s);
        }
    }
}

// kv[t,b,h,d,e] = sum_n k[t,b,h*32+d,n] * v[t,b,h*32+e,n]  (exact int in fp32)
__global__ __launch_bounds__(256) void kv_kernel(
    const float* __restrict__ k_s, const float* __restrict__ v_s,
    float* __restrict__ kv)
{
    const int blk = blockIdx.x;          // (t*BB+b)*HEADS + h
    const int h = blk & 7;
    const int m = blk >> 3;              // t*BB + b
    __shared__ float ks[32][65];
    __shared__ float vs[32][65];
    const int tid = threadIdx.x;
    const int d = tid >> 3;
    const int e0 = (tid & 7) * 4;
    float acc[4] = {0.f, 0.f, 0.f, 0.f};
    const size_t basek = ((size_t)m * CC + h * DD) * NN;
    for (int nc = 0; nc < NN; nc += 64) {
        for (int i = tid; i < 2048; i += 256) {
            int r = i >> 6, nl = i & 63;
            ks[r][nl] = k_s[basek + (size_t)r * NN + nc + nl];
            vs[r][nl] = v_s[basek + (size_t)r * NN + nc + nl];
        }
        __syncthreads();
        for (int nl = 0; nl < 64; ++nl) {
            float kd = ks[d][nl];
#pragma unroll
            for (int j = 0; j < 4; ++j) acc[j] += kd * vs[e0 + j][nl];
        }
        __syncthreads();
    }
#pragma unroll
    for (int j = 0; j < 4; ++j)
        kv[(size_t)blk * 1024 + d * 32 + e0 + j] = acc[j];
}

// a = 0.125 * q @ kv -> LIF(v_th=0.5); exact dyadic arithmetic in fp32.
__global__ __launch_bounds__(256) void attn_a_lif(
    const float* __restrict__ q_s, const float* __restrict__ kv,
    float* __restrict__ a_s)
{
    const int tid = threadIdx.x;
    const int n = blockIdx.x * 256 + tid;
    const int c = blockIdx.y;
    const int b = blockIdx.z;
    const int h = c >> 5;
    const int e = c & 31;
    __shared__ float kvs[TT][32];
    if (tid < 128) {
        int t = tid >> 5, d2 = tid & 31;
        kvs[t][d2] = kv[(((size_t)t * BB + b) * HEADS + h) * 1024 + d2 * 32 + e];
    }
    __syncthreads();
    float val[TT];
#pragma unroll
    for (int t = 0; t < TT; ++t) {
        float s = 0.f;
        const size_t qb = (((size_t)t * BB + b) * CC + h * DD) * NN + n;
#pragma unroll 8
        for (int d2 = 0; d2 < 32; ++d2)
            s += q_s[qb + (size_t)d2 * NN] * kvs[t][d2];
        val[t] = s * 0.125f;
    }
    float v = 0.f;
#pragma unroll
    for (int t = 0; t < TT; ++t) {
        v = v + (val[t] - v) * 0.5f;
        float s = (v >= 0.5f) ? 1.f : 0.f;
        a_s[(((size_t)t * BB + b) * CC + c) * NN + n] = s;
        v = v * (1.f - s);
    }
}

extern "C" void kernel_launch(void* const* d_in, const int* in_sizes, int n_in,
                              void* d_out, int out_size, void* d_ws, size_t ws_size,
                              hipStream_t stream)
{
    const float* x       = (const float*)d_in[0];
    const float* q_w     = (const float*)d_in[1];
    const float* q_bn    = (const float*)d_in[2];
    const float* k_w     = (const float*)d_in[3];
    const float* k_bn    = (const float*)d_in[4];
    const float* v_w     = (const float*)d_in[5];
    const float* v_bn    = (const float*)d_in[6];
    const float* proj_w  = (const float*)d_in[7];
    const float* proj_b  = (const float*)d_in[8];
    const float* proj_bn = (const float*)d_in[9];
    const float* mlp1_w  = (const float*)d_in[10];
    const float* mlp1_b  = (const float*)d_in[11];
    const float* mlp1_bn = (const float*)d_in[12];
    const float* mlp2_w  = (const float*)d_in[13];
    const float* mlp2_b  = (const float*)d_in[14];
    const float* mlp2_bn = (const float*)d_in[15];

    const size_t SZ = (size_t)TT * BB * CC * NN;   // 8388608 elements
    char* ws = (char*)d_ws;
    float*   q_s   = (float*)(ws);
    float*   k_s   = (float*)(ws + SZ * 4);
    float*   v_s   = (float*)(ws + 2 * SZ * 4);
    float*   a_s   = (float*)(ws + 3 * SZ * 4);
    float*   kvb   = (float*)(ws + 4 * SZ * 4);    // 1 MB
    float*   x_new = (float*)(ws);                 // reuses q_s region
    uint8_t* h1    = (uint8_t*)(ws + SZ * 4);      // reuses k_s region (33.5 MB)

    dim3 blk(256);
    dim3 gqkv(NN / 32, 3 * 256 / 32, BB);  // (32, 24, 8) fused q/k/v
    dim3 g256(NN / 32, 256 / 32, BB);      // (32, 8, 8)
    dim3 g1024(NN / 32, 1024 / 32, BB);    // (32, 32, 8)

    // Q/K/V conv + BN + LIF -> spike trains (f32 0/1), one fused dispatch
    conv_bn_lif_mfma<float, float, false, false, true, 256><<<gqkv, blk, 0, stream>>>(
        q_w, k_w, v_w, nullptr, q_bn, k_bn, v_bn, x, q_s, k_s, v_s,
        nullptr, 256);

    // attention: kv = k^T v, then a = 0.125 * q kv -> LIF(0.5)
    kv_kernel<<<dim3(TT * BB * HEADS), blk, 0, stream>>>(k_s, v_s, kvb);
    attn_a_lif<<<dim3(4, 256, 8), blk, 0, stream>>>(q_s, kvb, a_s);

    // proj conv + bias + BN + LIF, fused residual: x_new = x + ssa
    conv_bn_lif_mfma<float, float, true, true, false, 256><<<g256, blk, 0, stream>>>(
        proj_w, nullptr, nullptr, proj_b, proj_bn, nullptr, nullptr, a_s,
        x_new, nullptr, nullptr, x, 256);

    // MLP: 256 -> 1024 (spikes as uint8) -> 256, fused residual to d_out
    conv_bn_lif_mfma<float, uint8_t, true, false, false, 256><<<g1024, blk, 0, stream>>>(
        mlp1_w, nullptr, nullptr, mlp1_b, mlp1_bn, nullptr, nullptr, x_new,
        h1, nullptr, nullptr, nullptr, 1024);
    conv_bn_lif_mfma<uint8_t, float, true, true, false, 1024><<<g256, blk, 0, stream>>>(
        mlp2_w, nullptr, nullptr, mlp2_b, mlp2_bn, nullptr, nullptr, h1,
        (float*)d_out, nullptr, nullptr, x_new, 256);
}

// Round 9
// 1092.137 us; speedup vs baseline: 1.9778x; 1.5019x over previous
//
#include <hip/hip_runtime.h>
#include <cstdint>
#include <cstddef>

#define TT 4
#define BB 8
#define CC 256
#define NN 1024
#define HEADS 8
#define DD 32

typedef __attribute__((ext_vector_type(4))) double f64x4;

// Fused conv1x1 (GEMM) + BatchNorm + LIF-over-time using fp64 MFMA.
// Block: 64(o) x 64(n) x 4(t) tile; 4 waves, wave w = timestep w, each wave
// computes the full 64x64 tile for its t -> 128 MFMA (8192 cyc) per barrier,
// 4x round-6's amortization of the per-K-step barrier/staging drain.
// LDS: W^T[2][32][64] + X[2][4][32][64] = 81920 B -> 2 blocks/CU.
// Swizzle col' = (c + 16*(k&3)) & 63 on both tiles; read offset = 16*rowg
// (lane-constant) -> all GEMM ds_reads 2-way (free, m136).
// Reg-staged double-buffer, issue-early/write-late, 1 barrier per K-step.
// Epilogue: f64 pre-activations exchanged through LDS in two t-pair rounds
// (64 KB overlay on Xs); LIF state carried in registers between rounds.
// C/D mapping of v_mfma_f64_16x16x4f64 recovered at runtime via probes.
template<typename InT, typename OutT, bool HAS_BIAS, bool ADD_BASE, bool TRIPLE, int CIN>
__global__ __launch_bounds__(256, 2) void conv_bn_lif_mfma(
    const float* __restrict__ W0, const float* __restrict__ W1,
    const float* __restrict__ W2, const float* __restrict__ bias,
    const float* __restrict__ bn0, const float* __restrict__ bn1,
    const float* __restrict__ bn2,
    const InT* __restrict__ X,
    OutT* __restrict__ Out0, OutT* __restrict__ Out1, OutT* __restrict__ Out2,
    const float* __restrict__ base,   // [T, B, O, N] (ADD_BASE) or null
    int O)
{
    __shared__ __align__(16) float Ws[2][32][64];      // 16384 B, [buf][k][o']
    __shared__ __align__(16) float Xs[2][TT][32][64];  // 65536 B, [buf][t][k][n']
    double* pre = (double*)&Xs[0][0][0][0];            // [2][64][64] f64 overlay

    const int tid  = threadIdx.x;
    const int lane = tid & 63;
    const int wave = tid >> 6;          // == timestep t for the GEMM phase
    const int col  = lane & 15;
    const int rowg = lane >> 4;         // 0..3  (k-group)
    const int n0 = blockIdx.x * 64;
    const int b  = blockIdx.z;

    int o0;
    const float *W, *bn;
    OutT* Out;
    if constexpr (TRIPLE) {
        const int sel = blockIdx.y >> 2;
        o0 = (blockIdx.y & 3) * 64;
        W   = sel == 0 ? W0  : (sel == 1 ? W1  : W2);
        bn  = sel == 0 ? bn0 : (sel == 1 ? bn1 : bn2);
        Out = sel == 0 ? Out0 : (sel == 1 ? Out1 : Out2);
    } else {
        o0 = blockIdx.y * 64;
        W = W0; bn = bn0; Out = Out0;
    }

    // ---- runtime layout probes (exact integer arithmetic in f64) ----
    f64x4 p1 = {0.0, 0.0, 0.0, 0.0};
    f64x4 p2 = {0.0, 0.0, 0.0, 0.0};
    const double lanev = (double)col;
    p1 = __builtin_amdgcn_mfma_f64_16x16x4f64(lanev, 1.0, p1, 0, 0, 0);
    p2 = __builtin_amdgcn_mfma_f64_16x16x4f64(1.0, lanev, p2, 0, 0, 0);
    int o_idx[4], n_idx[4];
#pragma unroll
    for (int r = 0; r < 4; ++r) {
        o_idx[r] = (int)(p1[r] * 0.25);   // which A-row (o within 16) reg r holds
        n_idx[r] = (int)(p2[r] * 0.25);   // which B-col (n within 16) reg r holds
    }

    // swizzled read columns, shared by Ws and Xs (offset 16*rowg is lane-const)
    int ca[4];
#pragma unroll
    for (int i = 0; i < 4; ++i) ca[i] = (i * 16 + col + 16 * rowg) & 63;

    f64x4 acc[4][4];
#pragma unroll
    for (int mf = 0; mf < 4; ++mf)
#pragma unroll
        for (int nf = 0; nf < 4; ++nf)
            acc[mf][nf] = (f64x4){0.0, 0.0, 0.0, 0.0};

    // staging thread mapping (fixed): W 64o x 8 k-quads, X (t,k,n-quad)
    const int w_o = tid & 63, w_kq = tid >> 6;     // quads w_kq and w_kq+4

    float4 rW[2];
    float4 rX[8];
    uchar4 rXu[8];

    auto issue_loads = [&](int c0) {
        rW[0] = *reinterpret_cast<const float4*>(
            &W[(size_t)(o0 + w_o) * CIN + c0 + w_kq * 4]);
        rW[1] = *reinterpret_cast<const float4*>(
            &W[(size_t)(o0 + w_o) * CIN + c0 + (w_kq + 4) * 4]);
#pragma unroll
        for (int j = 0; j < 8; ++j) {
            const int lin = j * 256 + tid;
            const int t = lin >> 9, rem = lin & 511;
            const int kk = rem >> 4, n4 = rem & 15;
            const size_t goff =
                (((size_t)t * BB + b) * CIN + c0 + kk) * NN + n0 + n4 * 4;
            if constexpr (__is_same(InT, uint8_t)) {
                rXu[j] = *reinterpret_cast<const uchar4*>(&X[goff]);
            } else {
                rX[j] = *reinterpret_cast<const float4*>(&X[goff]);
            }
        }
    };
    auto write_tiles = [&](int buf) {
#pragma unroll
        for (int part = 0; part < 2; ++part) {
            const float* pv = reinterpret_cast<const float*>(&rW[part]);
#pragma unroll
            for (int e = 0; e < 4; ++e) {
                const int k = (w_kq + part * 4) * 4 + e;   // k&3 == e
                Ws[buf][k][(w_o + 16 * e) & 63] = pv[e];
            }
        }
#pragma unroll
        for (int j = 0; j < 8; ++j) {
            const int lin = j * 256 + tid;
            const int t = lin >> 9, rem = lin & 511;
            const int kk = rem >> 4, n4 = rem & 15;
            float4 xv;
            if constexpr (__is_same(InT, uint8_t)) {
                xv = make_float4((float)rXu[j].x, (float)rXu[j].y,
                                 (float)rXu[j].z, (float)rXu[j].w);
            } else {
                xv = rX[j];
            }
            const int cs = (n4 * 4 + 16 * (kk & 3)) & 63;  // quad-aligned swizzle
            *reinterpret_cast<float4*>(&Xs[buf][t][kk][cs]) = xv;
        }
    };

    // prologue: stage tile 0
    issue_loads(0);
    write_tiles(0);
    __syncthreads();

    int cur = 0;
    for (int c0 = 32; c0 <= CIN; c0 += 32) {
        if (c0 < CIN) issue_loads(c0);          // issue-early (hidden under MFMA)
        __builtin_amdgcn_s_setprio(1);
#pragma unroll
        for (int kq = 0; kq < 8; ++kq) {
            const int kr = kq * 4 + rowg;
            double av[4], bv[4];
#pragma unroll
            for (int i = 0; i < 4; ++i) {
                av[i] = (double)Ws[cur][kr][ca[i]];
                bv[i] = (double)Xs[cur][wave][kr][ca[i]];
            }
#pragma unroll
            for (int mf = 0; mf < 4; ++mf)
#pragma unroll
                for (int nf = 0; nf < 4; ++nf)
                    acc[mf][nf] = __builtin_amdgcn_mfma_f64_16x16x4f64(
                        av[mf], bv[nf], acc[mf][nf], 0, 0, 0);
        }
        __builtin_amdgcn_s_setprio(0);
        if (c0 < CIN) write_tiles(cur ^ 1);     // write-late
        __syncthreads();                        // single barrier per K-step
        cur ^= 1;
    }

    // ---- epilogue: two t-pair rounds through the 64 KB pre overlay ----
    auto dump_plane = [&](int slot) {
#pragma unroll
        for (int mf = 0; mf < 4; ++mf)
#pragma unroll
            for (int r = 0; r < 4; ++r)
#pragma unroll
                for (int nf = 0; nf < 4; ++nf)
                    pre[((size_t)slot * 64 + mf * 16 + o_idx[r]) * 64
                        + nf * 16 + n_idx[r]] = acc[mf][nf][r];
    };

    const int nl = tid & 63;
    const int og = wave;                 // thread handles o rows og*16..og*16+15
    double vst[16];

    // Round A: t = 0,1
    if (wave < 2) dump_plane(wave);
    __syncthreads();
#pragma unroll
    for (int i = 0; i < 16; ++i) {
        const int ol = og * 16 + i;
        const int o  = o0 + ol;
        const double g   = (double)bn[0 * O + o];
        const double be  = (double)bn[1 * O + o];
        const double mu  = (double)bn[2 * O + o];
        const double var = (double)bn[3 * O + o];
        const double scale = g / sqrt(var + 1e-5);
        double bi = 0.0;
        if constexpr (HAS_BIAS) bi = (double)bias[o];
        double v = 0.0;
#pragma unroll
        for (int t = 0; t < 2; ++t) {
            double val = (pre[((size_t)t * 64 + ol) * 64 + nl] + bi - mu) * scale + be;
            v = v + (val - v) * 0.5;
            double s = (v >= 1.0) ? 1.0 : 0.0;
            size_t idx = (((size_t)t * BB + b) * O + o) * NN + n0 + nl;
            if constexpr (ADD_BASE) {
                Out[idx] = (OutT)((double)base[idx] + s);
            } else {
                Out[idx] = (OutT)s;
            }
            v = v * (1.0 - s);
        }
        vst[i] = v;
    }
    __syncthreads();

    // Round B: t = 2,3
    if (wave >= 2) dump_plane(wave - 2);
    __syncthreads();
#pragma unroll
    for (int i = 0; i < 16; ++i) {
        const int ol = og * 16 + i;
        const int o  = o0 + ol;
        const double g   = (double)bn[0 * O + o];
        const double be  = (double)bn[1 * O + o];
        const double mu  = (double)bn[2 * O + o];
        const double var = (double)bn[3 * O + o];
        const double scale = g / sqrt(var + 1e-5);
        double bi = 0.0;
        if constexpr (HAS_BIAS) bi = (double)bias[o];
        double v = vst[i];
#pragma unroll
        for (int t = 2; t < 4; ++t) {
            double val = (pre[((size_t)(t - 2) * 64 + ol) * 64 + nl] + bi - mu) * scale + be;
            v = v + (val - v) * 0.5;
            double s = (v >= 1.0) ? 1.0 : 0.0;
            size_t idx = (((size_t)t * BB + b) * O + o) * NN + n0 + nl;
            if constexpr (ADD_BASE) {
                Out[idx] = (OutT)((double)base[idx] + s);
            } else {
                Out[idx] = (OutT)s;
            }
            v = v * (1.0 - s);
        }
    }
}

// kv[t,b,h,d,e] = sum_n k[t,b,h*32+d,n] * v[t,b,h*32+e,n]  (exact int in fp32)
__global__ __launch_bounds__(256) void kv_kernel(
    const float* __restrict__ k_s, const float* __restrict__ v_s,
    float* __restrict__ kv)
{
    const int blk = blockIdx.x;          // (t*BB+b)*HEADS + h
    const int h = blk & 7;
    const int m = blk >> 3;              // t*BB + b
    __shared__ float ks[32][65];
    __shared__ float vs[32][65];
    const int tid = threadIdx.x;
    const int d = tid >> 3;
    const int e0 = (tid & 7) * 4;
    float acc[4] = {0.f, 0.f, 0.f, 0.f};
    const size_t basek = ((size_t)m * CC + h * DD) * NN;
    for (int nc = 0; nc < NN; nc += 64) {
        for (int i = tid; i < 2048; i += 256) {
            int r = i >> 6, nl = i & 63;
            ks[r][nl] = k_s[basek + (size_t)r * NN + nc + nl];
            vs[r][nl] = v_s[basek + (size_t)r * NN + nc + nl];
        }
        __syncthreads();
        for (int nl = 0; nl < 64; ++nl) {
            float kd = ks[d][nl];
#pragma unroll
            for (int j = 0; j < 4; ++j) acc[j] += kd * vs[e0 + j][nl];
        }
        __syncthreads();
    }
#pragma unroll
    for (int j = 0; j < 4; ++j)
        kv[(size_t)blk * 1024 + d * 32 + e0 + j] = acc[j];
}

// a = 0.125 * q @ kv -> LIF(v_th=0.5); exact dyadic arithmetic in fp32.
__global__ __launch_bounds__(256) void attn_a_lif(
    const float* __restrict__ q_s, const float* __restrict__ kv,
    float* __restrict__ a_s)
{
    const int tid = threadIdx.x;
    const int n = blockIdx.x * 256 + tid;
    const int c = blockIdx.y;
    const int b = blockIdx.z;
    const int h = c >> 5;
    const int e = c & 31;
    __shared__ float kvs[TT][32];
    if (tid < 128) {
        int t = tid >> 5, d2 = tid & 31;
        kvs[t][d2] = kv[(((size_t)t * BB + b) * HEADS + h) * 1024 + d2 * 32 + e];
    }
    __syncthreads();
    float val[TT];
#pragma unroll
    for (int t = 0; t < TT; ++t) {
        float s = 0.f;
        const size_t qb = (((size_t)t * BB + b) * CC + h * DD) * NN + n;
#pragma unroll 8
        for (int d2 = 0; d2 < 32; ++d2)
            s += q_s[qb + (size_t)d2 * NN] * kvs[t][d2];
        val[t] = s * 0.125f;
    }
    float v = 0.f;
#pragma unroll
    for (int t = 0; t < TT; ++t) {
        v = v + (val[t] - v) * 0.5f;
        float s = (v >= 0.5f) ? 1.f : 0.f;
        a_s[(((size_t)t * BB + b) * CC + c) * NN + n] = s;
        v = v * (1.f - s);
    }
}

extern "C" void kernel_launch(void* const* d_in, const int* in_sizes, int n_in,
                              void* d_out, int out_size, void* d_ws, size_t ws_size,
                              hipStream_t stream)
{
    const float* x       = (const float*)d_in[0];
    const float* q_w     = (const float*)d_in[1];
    const float* q_bn    = (const float*)d_in[2];
    const float* k_w     = (const float*)d_in[3];
    const float* k_bn    = (const float*)d_in[4];
    const float* v_w     = (const float*)d_in[5];
    const float* v_bn    = (const float*)d_in[6];
    const float* proj_w  = (const float*)d_in[7];
    const float* proj_b  = (const float*)d_in[8];
    const float* proj_bn = (const float*)d_in[9];
    const float* mlp1_w  = (const float*)d_in[10];
    const float* mlp1_b  = (const float*)d_in[11];
    const float* mlp1_bn = (const float*)d_in[12];
    const float* mlp2_w  = (const float*)d_in[13];
    const float* mlp2_b  = (const float*)d_in[14];
    const float* mlp2_bn = (const float*)d_in[15];

    const size_t SZ = (size_t)TT * BB * CC * NN;   // 8388608 elements
    char* ws = (char*)d_ws;
    float*   q_s   = (float*)(ws);
    float*   k_s   = (float*)(ws + SZ * 4);
    float*   v_s   = (float*)(ws + 2 * SZ * 4);
    float*   a_s   = (float*)(ws + 3 * SZ * 4);
    float*   kvb   = (float*)(ws + 4 * SZ * 4);    // 1 MB
    float*   x_new = (float*)(ws);                 // reuses q_s region
    uint8_t* h1    = (uint8_t*)(ws + SZ * 4);      // reuses k_s region (33.5 MB)

    dim3 blk(256);
    dim3 gqkv(NN / 64, 3 * 256 / 64, BB);  // (16, 12, 8) fused q/k/v
    dim3 g256(NN / 64, 256 / 64, BB);      // (16, 4, 8)
    dim3 g1024(NN / 64, 1024 / 64, BB);    // (16, 16, 8)

    // Q/K/V conv + BN + LIF -> spike trains (f32 0/1), one fused dispatch
    conv_bn_lif_mfma<float, float, false, false, true, 256><<<gqkv, blk, 0, stream>>>(
        q_w, k_w, v_w, nullptr, q_bn, k_bn, v_bn, x, q_s, k_s, v_s,
        nullptr, 256);

    // attention: kv = k^T v, then a = 0.125 * q kv -> LIF(0.5)
    kv_kernel<<<dim3(TT * BB * HEADS), blk, 0, stream>>>(k_s, v_s, kvb);
    attn_a_lif<<<dim3(4, 256, 8), blk, 0, stream>>>(q_s, kvb, a_s);

    // proj conv + bias + BN + LIF, fused residual: x_new = x + ssa
    conv_bn_lif_mfma<float, float, true, true, false, 256><<<g256, blk, 0, stream>>>(
        proj_w, nullptr, nullptr, proj_b, proj_bn, nullptr, nullptr, a_s,
        x_new, nullptr, nullptr, x, 256);

    // MLP: 256 -> 1024 (spikes as uint8) -> 256, fused residual to d_out
    conv_bn_lif_mfma<float, uint8_t, true, false, false, 256><<<g1024, blk, 0, stream>>>(
        mlp1_w, nullptr, nullptr, mlp1_b, mlp1_bn, nullptr, nullptr, x_new,
        h1, nullptr, nullptr, nullptr, 1024);
    conv_bn_lif_mfma<uint8_t, float, true, true, false, 1024><<<g256, blk, 0, stream>>>(
        mlp2_w, nullptr, nullptr, mlp2_b, mlp2_bn, nullptr, nullptr, h1,
        (float*)d_out, nullptr, nullptr, x_new, 256);
}

// Round 10
// 1064.534 us; speedup vs baseline: 2.0291x; 1.0259x over previous
//
#include <hip/hip_runtime.h>
#include <cstdint>
#include <cstddef>

#define TT 4
#define BB 8
#define CC 256
#define NN 1024
#define HEADS 8
#define DD 32

typedef __attribute__((ext_vector_type(4))) double f64x4;

// ---------------------------------------------------------------------------
// conv32: 32(o) x 32(n) tile, 4 waves (wave = timestep), 4 blocks/CU.
// Round-6 structure (measured best for short-K convs: qkv fused, proj).
// LDS 40960 B: W^T[2][32][32] swizzled + X[2][4][32][32] swizzled.
// ---------------------------------------------------------------------------
template<typename InT, typename OutT, bool HAS_BIAS, bool ADD_BASE, bool TRIPLE>
__global__ __launch_bounds__(256, 4) void conv32_bn_lif(
    const float* __restrict__ W0, const float* __restrict__ W1,
    const float* __restrict__ W2, const float* __restrict__ bias,
    const float* __restrict__ bn0, const float* __restrict__ bn1,
    const float* __restrict__ bn2,
    const InT* __restrict__ X,
    OutT* __restrict__ Out0, OutT* __restrict__ Out1, OutT* __restrict__ Out2,
    const float* __restrict__ base,
    int O, int CIN)
{
    __shared__ __align__(16) float Ws[2][32][32];
    __shared__ __align__(16) float Xs[2][TT][32][32];
    double* pre = (double*)&Xs[0][0][0][0];            // [4][32][32] f64 overlay

    const int tid  = threadIdx.x;
    const int lane = tid & 63;
    const int wave = tid >> 6;
    const int col  = lane & 15;
    const int rowg = lane >> 4;
    const int n0 = blockIdx.x * 32;
    const int b  = blockIdx.z;

    int o0;
    const float *W, *bn;
    OutT* Out;
    if constexpr (TRIPLE) {
        const int sel = blockIdx.y >> 3;
        o0 = (blockIdx.y & 7) * 32;
        W   = sel == 0 ? W0  : (sel == 1 ? W1  : W2);
        bn  = sel == 0 ? bn0 : (sel == 1 ? bn1 : bn2);
        Out = sel == 0 ? Out0 : (sel == 1 ? Out1 : Out2);
    } else {
        o0 = blockIdx.y * 32;
        W = W0; bn = bn0; Out = Out0;
    }

    const int w_ol = tid >> 3, w_k4 = tid & 7;
    const int x_kk = tid >> 3, x_n4 = tid & 7;
    const int xsw  = (x_n4 * 4 + 8 * (x_kk & 3)) & 31;

    const int cb0 = (col + 8 * rowg) & 31;
    const int cb1 = (col + 16 + 8 * rowg) & 31;

    f64x4 p1 = {0.0, 0.0, 0.0, 0.0};
    f64x4 p2 = {0.0, 0.0, 0.0, 0.0};
    const double lanev = (double)col;
    p1 = __builtin_amdgcn_mfma_f64_16x16x4f64(lanev, 1.0, p1, 0, 0, 0);
    p2 = __builtin_amdgcn_mfma_f64_16x16x4f64(1.0, lanev, p2, 0, 0, 0);
    int o_idx[4], n_idx[4];
#pragma unroll
    for (int r = 0; r < 4; ++r) {
        o_idx[r] = (int)(p1[r] * 0.25);
        n_idx[r] = (int)(p2[r] * 0.25);
    }

    f64x4 acc[2][2];
#pragma unroll
    for (int mf = 0; mf < 2; ++mf)
#pragma unroll
        for (int nf = 0; nf < 2; ++nf)
            acc[mf][nf] = (f64x4){0.0, 0.0, 0.0, 0.0};

    float4 rW;
    float4 rX[TT];
    uchar4 rXu[TT];

    auto issue_loads = [&](int c0) {
        rW = *reinterpret_cast<const float4*>(
            &W[(size_t)(o0 + w_ol) * CIN + c0 + w_k4 * 4]);
#pragma unroll
        for (int j = 0; j < TT; ++j) {
            const size_t goff =
                (((size_t)j * BB + b) * CIN + c0 + x_kk) * NN + n0 + x_n4 * 4;
            if constexpr (__is_same(InT, uint8_t)) {
                rXu[j] = *reinterpret_cast<const uchar4*>(&X[goff]);
            } else {
                rX[j] = *reinterpret_cast<const float4*>(&X[goff]);
            }
        }
    };
    auto write_tiles = [&](int buf) {
        Ws[buf][w_k4 * 4 + 0][(w_ol + 0 ) & 31] = rW.x;
        Ws[buf][w_k4 * 4 + 1][(w_ol + 8 ) & 31] = rW.y;
        Ws[buf][w_k4 * 4 + 2][(w_ol + 16) & 31] = rW.z;
        Ws[buf][w_k4 * 4 + 3][(w_ol + 24) & 31] = rW.w;
#pragma unroll
        for (int j = 0; j < TT; ++j) {
            float4 xv;
            if constexpr (__is_same(InT, uint8_t)) {
                xv = make_float4((float)rXu[j].x, (float)rXu[j].y,
                                 (float)rXu[j].z, (float)rXu[j].w);
            } else {
                xv = rX[j];
            }
            *reinterpret_cast<float4*>(&Xs[buf][j][x_kk][xsw]) = xv;
        }
    };

    issue_loads(0);
    write_tiles(0);
    __syncthreads();

    int cur = 0;
    for (int c0 = 32; c0 <= CIN; c0 += 32) {
        const bool has_next = (c0 < CIN);
        if (has_next) issue_loads(c0);
        __builtin_amdgcn_s_setprio(1);
#pragma unroll
        for (int k0 = 0; k0 < 32; k0 += 4) {
            const int kr = k0 + rowg;
            double av0 = (double)Ws[cur][kr][cb0];
            double av1 = (double)Ws[cur][kr][cb1];
            double bv0 = (double)Xs[cur][wave][kr][cb0];
            double bv1 = (double)Xs[cur][wave][kr][cb1];
            acc[0][0] = __builtin_amdgcn_mfma_f64_16x16x4f64(av0, bv0, acc[0][0], 0, 0, 0);
            acc[1][0] = __builtin_amdgcn_mfma_f64_16x16x4f64(av1, bv0, acc[1][0], 0, 0, 0);
            acc[0][1] = __builtin_amdgcn_mfma_f64_16x16x4f64(av0, bv1, acc[0][1], 0, 0, 0);
            acc[1][1] = __builtin_amdgcn_mfma_f64_16x16x4f64(av1, bv1, acc[1][1], 0, 0, 0);
        }
        __builtin_amdgcn_s_setprio(0);
        if (has_next) write_tiles(cur ^ 1);
        __syncthreads();
        cur ^= 1;
    }

#pragma unroll
    for (int mf = 0; mf < 2; ++mf)
#pragma unroll
        for (int r = 0; r < 4; ++r)
#pragma unroll
            for (int nf = 0; nf < 2; ++nf)
                pre[((size_t)wave * 32 + mf * 16 + o_idx[r]) * 32
                    + nf * 16 + n_idx[r]] = acc[mf][nf][r];
    __syncthreads();

    const int nl = tid & 31;
    const int obase = (tid >> 5) * 4;
#pragma unroll
    for (int i = 0; i < 4; ++i) {
        const int ol = obase + i;
        const int o  = o0 + ol;
        const double g   = (double)bn[0 * O + o];
        const double be  = (double)bn[1 * O + o];
        const double mu  = (double)bn[2 * O + o];
        const double var = (double)bn[3 * O + o];
        const double scale = g / sqrt(var + 1e-5);
        double bi = 0.0;
        if constexpr (HAS_BIAS) bi = (double)bias[o];
        double v = 0.0;
#pragma unroll
        for (int t = 0; t < TT; ++t) {
            double val = (pre[((size_t)t * 32 + ol) * 32 + nl] + bi - mu) * scale + be;
            v = v + (val - v) * 0.5;
            double s = (v >= 1.0) ? 1.0 : 0.0;
            size_t idx = (((size_t)t * BB + b) * O + o) * NN + n0 + nl;
            if constexpr (ADD_BASE) {
                Out[idx] = (OutT)((double)base[idx] + s);
            } else {
                Out[idx] = (OutT)s;
            }
            v = v * (1.0 - s);
        }
    }
}

// ---------------------------------------------------------------------------
// conv64: 64(o) x 64(n) tile, 4 waves (wave = timestep), 2 blocks/CU.
// Round-9 structure (measured best for CIN-heavy convs: mlp1, mlp2).
// LDS 81920 B: W^T[2][32][64] + X[2][4][32][64], swizzled; 128 MFMA/barrier.
// ---------------------------------------------------------------------------
template<typename InT, typename OutT, bool HAS_BIAS, bool ADD_BASE, int CIN>
__global__ __launch_bounds__(256, 2) void conv64_bn_lif(
    const float* __restrict__ W,
    const float* __restrict__ bias,
    const float* __restrict__ bn,
    const InT* __restrict__ X,
    OutT* __restrict__ Out,
    const float* __restrict__ base,
    int O)
{
    __shared__ __align__(16) float Ws[2][32][64];
    __shared__ __align__(16) float Xs[2][TT][32][64];
    double* pre = (double*)&Xs[0][0][0][0];            // [2][64][64] f64 overlay

    const int tid  = threadIdx.x;
    const int lane = tid & 63;
    const int wave = tid >> 6;
    const int col  = lane & 15;
    const int rowg = lane >> 4;
    const int n0 = blockIdx.x * 64;
    const int o0 = blockIdx.y * 64;
    const int b  = blockIdx.z;

    f64x4 p1 = {0.0, 0.0, 0.0, 0.0};
    f64x4 p2 = {0.0, 0.0, 0.0, 0.0};
    const double lanev = (double)col;
    p1 = __builtin_amdgcn_mfma_f64_16x16x4f64(lanev, 1.0, p1, 0, 0, 0);
    p2 = __builtin_amdgcn_mfma_f64_16x16x4f64(1.0, lanev, p2, 0, 0, 0);
    int o_idx[4], n_idx[4];
#pragma unroll
    for (int r = 0; r < 4; ++r) {
        o_idx[r] = (int)(p1[r] * 0.25);
        n_idx[r] = (int)(p2[r] * 0.25);
    }

    int ca[4];
#pragma unroll
    for (int i = 0; i < 4; ++i) ca[i] = (i * 16 + col + 16 * rowg) & 63;

    f64x4 acc[4][4];
#pragma unroll
    for (int mf = 0; mf < 4; ++mf)
#pragma unroll
        for (int nf = 0; nf < 4; ++nf)
            acc[mf][nf] = (f64x4){0.0, 0.0, 0.0, 0.0};

    const int w_o = tid & 63, w_kq = tid >> 6;

    float4 rW[2];
    float4 rX[8];
    uchar4 rXu[8];

    auto issue_loads = [&](int c0) {
        rW[0] = *reinterpret_cast<const float4*>(
            &W[(size_t)(o0 + w_o) * CIN + c0 + w_kq * 4]);
        rW[1] = *reinterpret_cast<const float4*>(
            &W[(size_t)(o0 + w_o) * CIN + c0 + (w_kq + 4) * 4]);
#pragma unroll
        for (int j = 0; j < 8; ++j) {
            const int lin = j * 256 + tid;
            const int t = lin >> 9, rem = lin & 511;
            const int kk = rem >> 4, n4 = rem & 15;
            const size_t goff =
                (((size_t)t * BB + b) * CIN + c0 + kk) * NN + n0 + n4 * 4;
            if constexpr (__is_same(InT, uint8_t)) {
                rXu[j] = *reinterpret_cast<const uchar4*>(&X[goff]);
            } else {
                rX[j] = *reinterpret_cast<const float4*>(&X[goff]);
            }
        }
    };
    auto write_tiles = [&](int buf) {
#pragma unroll
        for (int part = 0; part < 2; ++part) {
            const float* pv = reinterpret_cast<const float*>(&rW[part]);
#pragma unroll
            for (int e = 0; e < 4; ++e) {
                const int k = (w_kq + part * 4) * 4 + e;
                Ws[buf][k][(w_o + 16 * e) & 63] = pv[e];
            }
        }
#pragma unroll
        for (int j = 0; j < 8; ++j) {
            const int lin = j * 256 + tid;
            const int t = lin >> 9, rem = lin & 511;
            const int kk = rem >> 4, n4 = rem & 15;
            float4 xv;
            if constexpr (__is_same(InT, uint8_t)) {
                xv = make_float4((float)rXu[j].x, (float)rXu[j].y,
                                 (float)rXu[j].z, (float)rXu[j].w);
            } else {
                xv = rX[j];
            }
            const int cs = (n4 * 4 + 16 * (kk & 3)) & 63;
            *reinterpret_cast<float4*>(&Xs[buf][t][kk][cs]) = xv;
        }
    };

    issue_loads(0);
    write_tiles(0);
    __syncthreads();

    int cur = 0;
    for (int c0 = 32; c0 <= CIN; c0 += 32) {
        if (c0 < CIN) issue_loads(c0);
        __builtin_amdgcn_s_setprio(1);
#pragma unroll
        for (int kq = 0; kq < 8; ++kq) {
            const int kr = kq * 4 + rowg;
            double av[4], bv[4];
#pragma unroll
            for (int i = 0; i < 4; ++i) {
                av[i] = (double)Ws[cur][kr][ca[i]];
                bv[i] = (double)Xs[cur][wave][kr][ca[i]];
            }
#pragma unroll
            for (int mf = 0; mf < 4; ++mf)
#pragma unroll
                for (int nf = 0; nf < 4; ++nf)
                    acc[mf][nf] = __builtin_amdgcn_mfma_f64_16x16x4f64(
                        av[mf], bv[nf], acc[mf][nf], 0, 0, 0);
        }
        __builtin_amdgcn_s_setprio(0);
        if (c0 < CIN) write_tiles(cur ^ 1);
        __syncthreads();
        cur ^= 1;
    }

    auto dump_plane = [&](int slot) {
#pragma unroll
        for (int mf = 0; mf < 4; ++mf)
#pragma unroll
            for (int r = 0; r < 4; ++r)
#pragma unroll
                for (int nf = 0; nf < 4; ++nf)
                    pre[((size_t)slot * 64 + mf * 16 + o_idx[r]) * 64
                        + nf * 16 + n_idx[r]] = acc[mf][nf][r];
    };

    const int nl = tid & 63;
    const int og = wave;
    double vst[16];

    if (wave < 2) dump_plane(wave);
    __syncthreads();
#pragma unroll
    for (int i = 0; i < 16; ++i) {
        const int ol = og * 16 + i;
        const int o  = o0 + ol;
        const double g   = (double)bn[0 * O + o];
        const double be  = (double)bn[1 * O + o];
        const double mu  = (double)bn[2 * O + o];
        const double var = (double)bn[3 * O + o];
        const double scale = g / sqrt(var + 1e-5);
        double bi = 0.0;
        if constexpr (HAS_BIAS) bi = (double)bias[o];
        double v = 0.0;
#pragma unroll
        for (int t = 0; t < 2; ++t) {
            double val = (pre[((size_t)t * 64 + ol) * 64 + nl] + bi - mu) * scale + be;
            v = v + (val - v) * 0.5;
            double s = (v >= 1.0) ? 1.0 : 0.0;
            size_t idx = (((size_t)t * BB + b) * O + o) * NN + n0 + nl;
            if constexpr (ADD_BASE) {
                Out[idx] = (OutT)((double)base[idx] + s);
            } else {
                Out[idx] = (OutT)s;
            }
            v = v * (1.0 - s);
        }
        vst[i] = v;
    }
    __syncthreads();

    if (wave >= 2) dump_plane(wave - 2);
    __syncthreads();
#pragma unroll
    for (int i = 0; i < 16; ++i) {
        const int ol = og * 16 + i;
        const int o  = o0 + ol;
        const double g   = (double)bn[0 * O + o];
        const double be  = (double)bn[1 * O + o];
        const double mu  = (double)bn[2 * O + o];
        const double var = (double)bn[3 * O + o];
        const double scale = g / sqrt(var + 1e-5);
        double bi = 0.0;
        if constexpr (HAS_BIAS) bi = (double)bias[o];
        double v = vst[i];
#pragma unroll
        for (int t = 2; t < 4; ++t) {
            double val = (pre[((size_t)(t - 2) * 64 + ol) * 64 + nl] + bi - mu) * scale + be;
            v = v + (val - v) * 0.5;
            double s = (v >= 1.0) ? 1.0 : 0.0;
            size_t idx = (((size_t)t * BB + b) * O + o) * NN + n0 + nl;
            if constexpr (ADD_BASE) {
                Out[idx] = (OutT)((double)base[idx] + s);
            } else {
                Out[idx] = (OutT)s;
            }
            v = v * (1.0 - s);
        }
    }
}

// kv[t,b,h,d,e] = sum_n k[t,b,h*32+d,n] * v[t,b,h*32+e,n]  (exact int in fp32)
__global__ __launch_bounds__(256) void kv_kernel(
    const float* __restrict__ k_s, const float* __restrict__ v_s,
    float* __restrict__ kv)
{
    const int blk = blockIdx.x;
    const int h = blk & 7;
    const int m = blk >> 3;
    __shared__ float ks[32][65];
    __shared__ float vs[32][65];
    const int tid = threadIdx.x;
    const int d = tid >> 3;
    const int e0 = (tid & 7) * 4;
    float acc[4] = {0.f, 0.f, 0.f, 0.f};
    const size_t basek = ((size_t)m * CC + h * DD) * NN;
    for (int nc = 0; nc < NN; nc += 64) {
        for (int i = tid; i < 2048; i += 256) {
            int r = i >> 6, nl = i & 63;
            ks[r][nl] = k_s[basek + (size_t)r * NN + nc + nl];
            vs[r][nl] = v_s[basek + (size_t)r * NN + nc + nl];
        }
        __syncthreads();
        for (int nl = 0; nl < 64; ++nl) {
            float kd = ks[d][nl];
#pragma unroll
            for (int j = 0; j < 4; ++j) acc[j] += kd * vs[e0 + j][nl];
        }
        __syncthreads();
    }
#pragma unroll
    for (int j = 0; j < 4; ++j)
        kv[(size_t)blk * 1024 + d * 32 + e0 + j] = acc[j];
}

// a = 0.125 * q @ kv -> LIF(v_th=0.5); exact dyadic arithmetic in fp32.
__global__ __launch_bounds__(256) void attn_a_lif(
    const float* __restrict__ q_s, const float* __restrict__ kv,
    float* __restrict__ a_s)
{
    const int tid = threadIdx.x;
    const int n = blockIdx.x * 256 + tid;
    const int c = blockIdx.y;
    const int b = blockIdx.z;
    const int h = c >> 5;
    const int e = c & 31;
    __shared__ float kvs[TT][32];
    if (tid < 128) {
        int t = tid >> 5, d2 = tid & 31;
        kvs[t][d2] = kv[(((size_t)t * BB + b) * HEADS + h) * 1024 + d2 * 32 + e];
    }
    __syncthreads();
    float val[TT];
#pragma unroll
    for (int t = 0; t < TT; ++t) {
        float s = 0.f;
        const size_t qb = (((size_t)t * BB + b) * CC + h * DD) * NN + n;
#pragma unroll 8
        for (int d2 = 0; d2 < 32; ++d2)
            s += q_s[qb + (size_t)d2 * NN] * kvs[t][d2];
        val[t] = s * 0.125f;
    }
    float v = 0.f;
#pragma unroll
    for (int t = 0; t < TT; ++t) {
        v = v + (val[t] - v) * 0.5f;
        float s = (v >= 0.5f) ? 1.f : 0.f;
        a_s[(((size_t)t * BB + b) * CC + c) * NN + n] = s;
        v = v * (1.f - s);
    }
}

extern "C" void kernel_launch(void* const* d_in, const int* in_sizes, int n_in,
                              void* d_out, int out_size, void* d_ws, size_t ws_size,
                              hipStream_t stream)
{
    const float* x       = (const float*)d_in[0];
    const float* q_w     = (const float*)d_in[1];
    const float* q_bn    = (const float*)d_in[2];
    const float* k_w     = (const float*)d_in[3];
    const float* k_bn    = (const float*)d_in[4];
    const float* v_w     = (const float*)d_in[5];
    const float* v_bn    = (const float*)d_in[6];
    const float* proj_w  = (const float*)d_in[7];
    const float* proj_b  = (const float*)d_in[8];
    const float* proj_bn = (const float*)d_in[9];
    const float* mlp1_w  = (const float*)d_in[10];
    const float* mlp1_b  = (const float*)d_in[11];
    const float* mlp1_bn = (const float*)d_in[12];
    const float* mlp2_w  = (const float*)d_in[13];
    const float* mlp2_b  = (const float*)d_in[14];
    const float* mlp2_bn = (const float*)d_in[15];

    const size_t SZ = (size_t)TT * BB * CC * NN;   // 8388608 elements
    char* ws = (char*)d_ws;
    float*   q_s   = (float*)(ws);
    float*   k_s   = (float*)(ws + SZ * 4);
    float*   v_s   = (float*)(ws + 2 * SZ * 4);
    float*   a_s   = (float*)(ws + 3 * SZ * 4);
    float*   kvb   = (float*)(ws + 4 * SZ * 4);    // 1 MB
    float*   x_new = (float*)(ws);                 // reuses q_s region
    uint8_t* h1    = (uint8_t*)(ws + SZ * 4);      // reuses k_s region (33.5 MB)

    dim3 blk(256);
    dim3 gqkv32(NN / 32, 3 * 256 / 32, BB);   // (32, 24, 8) fused q/k/v
    dim3 g256_32(NN / 32, 256 / 32, BB);      // (32, 8, 8) proj
    dim3 g1024_64(NN / 64, 1024 / 64, BB);    // (16, 16, 8) mlp1
    dim3 g256_64(NN / 64, 256 / 64, BB);      // (16, 4, 8)  mlp2

    // Q/K/V conv + BN + LIF -> spike trains (f32 0/1), one fused dispatch (32x32)
    conv32_bn_lif<float, float, false, false, true><<<gqkv32, blk, 0, stream>>>(
        q_w, k_w, v_w, nullptr, q_bn, k_bn, v_bn, x, q_s, k_s, v_s,
        nullptr, 256, 256);

    // attention: kv = k^T v, then a = 0.125 * q kv -> LIF(0.5)
    kv_kernel<<<dim3(TT * BB * HEADS), blk, 0, stream>>>(k_s, v_s, kvb);
    attn_a_lif<<<dim3(4, 256, 8), blk, 0, stream>>>(q_s, kvb, a_s);

    // proj conv + bias + BN + LIF, fused residual: x_new = x + ssa (32x32)
    conv32_bn_lif<float, float, true, true, false><<<g256_32, blk, 0, stream>>>(
        proj_w, nullptr, nullptr, proj_b, proj_bn, nullptr, nullptr, a_s,
        x_new, nullptr, nullptr, x, 256, 256);

    // MLP: 256 -> 1024 (spikes as uint8) -> 256, fused residual to d_out (64x64)
    conv64_bn_lif<float, uint8_t, true, false, 256><<<g1024_64, blk, 0, stream>>>(
        mlp1_w, mlp1_b, mlp1_bn, x_new, h1, nullptr, 1024);
    conv64_bn_lif<uint8_t, float, true, true, 1024><<<g256_64, blk, 0, stream>>>(
        mlp2_w, mlp2_b, mlp2_bn, h1, (float*)d_out, x_new, 256);
}